// Round 10
// baseline (481.516 us; speedup 1.0000x reference)
//
#include <hip/hip_runtime.h>
#include <hip/hip_bf16.h>
#include <hip/hip_fp16.h>

typedef unsigned short u16;
typedef __attribute__((ext_vector_type(8))) short short8;
typedef __attribute__((ext_vector_type(4))) float floatx4;

#define DEVI static __device__ __forceinline__

DEVI float bf2f(u16 b) { return __uint_as_float(((unsigned)b) << 16); }
DEVI u16 f2bf(float f) {
  __hip_bfloat16 h = __float2bfloat16(f);
  u16 u; __builtin_memcpy(&u, &h, 2); return u;
}
DEVI u16 f2h(float f) {
  __half h = __float2half(f);
  u16 u; __builtin_memcpy(&u, &h, 2); return u;
}

// async global->LDS, 16B per lane; LDS dest = wave-uniform base + lane*16
DEVI void async_ld16(const u16* g, u16* l) {
  __builtin_amdgcn_global_load_lds(
      (const __attribute__((address_space(1))) unsigned int*)g,
      (__attribute__((address_space(3))) unsigned int*)l, 16, 0, 0);
}

// DPP cross-lane add on float (VALU pipe)
template <int CTRL>
DEVI float dpp_add_f(float v) {
  int i; __builtin_memcpy(&i, &v, 4);
  int p = __builtin_amdgcn_update_dpp(0, i, CTRL, 0xF, 0xF, false);
  float pv; __builtin_memcpy(&pv, &p, 4);
  return v + pv;
}

// head-major permutation: feature f (= d*8+h) -> c' = h*64+d
DEVI int hperm(int f) { return ((f & 7) << 6) | (f >> 3); }

// ---------------- weight transpose + fp32->bf16: dst[C][R] = bf16(src[R][C]^T) ----------------
struct TransArgs {
  const float* src[10];
  u16* dst[10];
  int R[10];
  int C[10];
};

__global__ __launch_bounds__(256) void transpose_k(TransArgs t) {
  const int z = blockIdx.z;
  const float* __restrict__ src = t.src[z];
  u16* __restrict__ dst = t.dst[z];
  const int R = t.R[z], C = t.C[z];
  const int c0 = blockIdx.x * 32, r0 = blockIdx.y * 32;
  if (c0 >= C || r0 >= R) return;
  __shared__ float tile[32][33];
  const int tx = threadIdx.x & 31, ty = threadIdx.x >> 5;
  for (int i = ty; i < 32; i += 8)
    tile[i][tx] = src[(size_t)(r0 + i) * C + c0 + tx];
  __syncthreads();
  for (int i = ty; i < 32; i += 8) {
    const int f = r0 + tx;
    const int fi = (z == 9) ? hperm(f) : f;
    dst[(size_t)(c0 + i) * R + fi] = f2bf(tile[tx][i]);
  }
}

// ---------------- fp32 -> bf16 convert for KEY/QUERY/VALUE ----------------
struct ConvArgs {
  const float* src[3];
  u16* dst[3];
};

__global__ __launch_bounds__(256) void conv_k(ConvArgs c) {
  const int z = blockIdx.z;
  const float* __restrict__ src = c.src[z];
  u16* __restrict__ dst = c.dst[z];
  const size_t i = ((size_t)blockIdx.x * 256 + threadIdx.x) * 8;
  const float4 f0 = *(const float4*)(src + i);
  const float4 f1 = *(const float4*)(src + i + 4);
  u16 tmp[8] = {f2bf(f0.x), f2bf(f0.y), f2bf(f0.z), f2bf(f0.w),
                f2bf(f1.x), f2bf(f1.y), f2bf(f1.z), f2bf(f1.w)};
  int4 t; __builtin_memcpy(&t, tmp, 16);
  *(int4*)(dst + i) = t;
}

// ------------- GEMM 128x128 tile, async global->LDS staging -------------
// A bf16 [M][K]; WT bf16 [N][K]. Unpadded [128][64] LDS tiles, XOR-swizzled granules:
// row r, phys granule p holds logical granule p ^ (r&7). Swizzle applied on the GLOBAL
// address side (LDS side is hardware lane*16). Fragment reads: phys = (ks*4+quad)^(lane&7)
// -> 2 lanes per bank group (free). c_mode: 0=bf16, 1=fp32, 2=fp16. out_perm: head-major col.
struct GemmArgs {
  const u16* A[3];
  const u16* WT[3];
  const float* bias[3];
  void* C[3];
};

__global__ __launch_bounds__(256, 3) void gemm128(GemmArgs ga, int M, int N, int K,
                                                  int relu, int c_mode, int out_perm) {
  const int z = blockIdx.z;
  const u16* __restrict__ A = ga.A[z];
  const u16* __restrict__ WT = ga.WT[z];
  const float* __restrict__ bias = ga.bias[z];
  void* __restrict__ C = ga.C[z];

  __shared__ u16 As[128 * 64];
  __shared__ u16 Bs[128 * 64];

  const int tid = threadIdx.x;
  const int lane = tid & 63;
  const int wave = tid >> 6;
  const int wm = wave >> 1, wn = wave & 1;
  const int mb = blockIdx.y, nb = blockIdx.x;

  floatx4 acc[4][4];
#pragma unroll
  for (int mi = 0; mi < 4; ++mi)
#pragma unroll
    for (int ni = 0; ni < 4; ++ni) acc[mi][ni] = floatx4{0.f, 0.f, 0.f, 0.f};

  // staging: lane covers row (lane>>3) of an 8-row strip, phys granule (lane&7);
  // global column granule = phys ^ (row&7) = (lane&7) ^ ((lane>>3)&7)
  const int g = (lane & 7) ^ ((lane >> 3) & 7);
  const int srow = lane >> 3;
  const size_t aRowBase = (size_t)(mb * 128 + wave * 32 + srow) * K + g * 8;
  const size_t bRowBase = (size_t)(nb * 128 + wave * 32 + srow) * K + g * 8;

  for (int k0 = 0; k0 < K; k0 += 64) {
    __syncthreads();
#pragma unroll
    for (int it = 0; it < 4; ++it) {
      async_ld16(A + aRowBase + (size_t)it * 8 * K + k0, As + (wave * 32 + it * 8) * 64);
      async_ld16(WT + bRowBase + (size_t)it * 8 * K + k0, Bs + (wave * 32 + it * 8) * 64);
    }
    __syncthreads();
#pragma unroll
    for (int ks = 0; ks < 2; ++ks) {
      const int phys = ((ks * 4 + (lane >> 4)) ^ (lane & 7)) * 8;
      short8 af[4], bf[4];
#pragma unroll
      for (int i = 0; i < 4; ++i) {
        const int m = wm * 64 + i * 16 + (lane & 15);
        const int n = wn * 64 + i * 16 + (lane & 15);
        af[i] = *(const short8*)(As + m * 64 + phys);
        bf[i] = *(const short8*)(Bs + n * 64 + phys);
      }
#pragma unroll
      for (int mi = 0; mi < 4; ++mi)
#pragma unroll
        for (int ni = 0; ni < 4; ++ni)
          acc[mi][ni] = __builtin_amdgcn_mfma_f32_16x16x32_bf16(af[mi], bf[ni], acc[mi][ni], 0, 0, 0);
    }
  }

  // C/D layout: col = lane&15, row = (lane>>4)*4 + reg
#pragma unroll
  for (int mi = 0; mi < 4; ++mi)
#pragma unroll
    for (int ni = 0; ni < 4; ++ni) {
      const int col = nb * 128 + wn * 64 + ni * 16 + (lane & 15);
      const float bv = bias[col];
      const int colw = out_perm ? hperm(col) : col;
      const floatx4 v = acc[mi][ni];
#pragma unroll
      for (int r = 0; r < 4; ++r) {
        const int row = mb * 128 + wm * 64 + mi * 16 + (lane >> 4) * 4 + r;
        float x = v[r] + bv;
        if (relu) x = fmaxf(x, 0.f);
        if (c_mode == 1)      ((float*)C)[(size_t)row * N + colw] = x;
        else if (c_mode == 2) ((u16*)C)[(size_t)row * N + colw] = f2h(x);
        else                  ((u16*)C)[(size_t)row * N + colw] = f2bf(x);
      }
    }
}

// ---------------- fused attention v6 (head-major, 8 q/wave, 4 blocks/CU) ----------------
// K,Q,V fp16 [b*1024][512], feature layout c' = h*64+d. Wave-autonomous:
// wid -> (b, sp 0..15, qt 0..127); 8 queries/wave, 64 keys/wave.
// lane = (qg 0..3, h 0..7, half 0..1): queries {j0+qg, j0+qg+4}, slice = 32 contiguous
// feats, 4 b128 granules rotated by h. 2-key chunks, PHASE-SEPARATED (cdist x2 ->
// softmax x2 -> PV x2) for ILP. Live regs ~112 <= 128 cap -> 4 waves/SIMD, no spill.
__global__ __launch_bounds__(256, 4) void attn_kernel(const u16* __restrict__ Km,
                                                      const u16* __restrict__ Qm,
                                                      const u16* __restrict__ Vm,
                                                      u16* __restrict__ partial) {
  __shared__ alignas(16) u16 lds[4 * 2048];   // per wave: K rows [0,1024), V rows [1024,2048)

  const int tid = threadIdx.x;
  const int lane = tid & 63;
  const int wave = tid >> 6;
  const int wid = blockIdx.x * 4 + wave;      // 0..8191
  const int qt = wid & 127;
  const int sp = (wid >> 7) & 15;
  const int b = wid >> 11;
  const int j0 = qt * 8;

  const int qg = lane >> 4;
  const int h = (lane >> 1) & 7;
  const int half = lane & 1;

  int grans[4];
#pragma unroll
  for (int pi = 0; pi < 4; ++pi)
    grans[pi] = h * 8 + half * 4 + ((pi + h) & 3);

  // Q into registers: 2 queries x 4 granules (rotated order)
  int4 Qr[2][4];
#pragma unroll
  for (int qi = 0; qi < 2; ++qi) {
    const u16* qrow = Qm + (size_t)(b * 1024 + j0 + qg + qi * 4) * 512;
#pragma unroll
    for (int pi = 0; pi < 4; ++pi)
      Qr[qi][pi] = *(const int4*)(qrow + grans[pi] * 8);
  }

  __half2 o[2][4][4];   // [qi][pi][j]
#pragma unroll
  for (int qi = 0; qi < 2; ++qi)
#pragma unroll
    for (int pi = 0; pi < 4; ++pi)
#pragma unroll
      for (int j = 0; j < 4; ++j) o[qi][pi][j] = __float2half2_rn(0.f);

  u16* Kw = lds + wave * 2048;
  u16* Vw = Kw + 1024;
  const int keyBase = b * 1024 + sp * 64;

  int4 Kp[2], Vp[2];
#pragma unroll
  for (int r = 0; r < 2; ++r) {
    const size_t ga = (size_t)(keyBase + r) * 512 + lane * 8;
    Kp[r] = *(const int4*)(Km + ga);
    Vp[r] = *(const int4*)(Vm + ga);
  }

#pragma unroll 1
  for (int t = 0; t < 32; ++t) {
    // stage current 2-key chunk (lane writes granule=lane; conflict-free)
#pragma unroll
    for (int r = 0; r < 2; ++r) {
      *(int4*)(Kw + r * 512 + lane * 8) = Kp[r];
      *(int4*)(Vw + r * 512 + lane * 8) = Vp[r];
    }
    // prefetch next chunk
    if (t < 31) {
#pragma unroll
      for (int r = 0; r < 2; ++r) {
        const size_t ga = (size_t)(keyBase + (t + 1) * 2 + r) * 512 + lane * 8;
        Kp[r] = *(const int4*)(Km + ga);
        Vp[r] = *(const int4*)(Vm + ga);
      }
    }

    // ---- phase A: cdist for both keys (independent chains, ILP)
    __half2 acc[2][2][2];   // [r][qi][j]
#pragma unroll
    for (int r = 0; r < 2; ++r) {
      const u16* krow = Kw + r * 512;
#pragma unroll
      for (int qi = 0; qi < 2; ++qi) {
        acc[r][qi][0] = __float2half2_rn(0.f);
        acc[r][qi][1] = __float2half2_rn(0.f);
      }
#pragma unroll
      for (int pi = 0; pi < 4; ++pi) {
        const int4 kv = *(const int4*)(krow + grans[pi] * 8);
        const __half2* kh = reinterpret_cast<const __half2*>(&kv);
#pragma unroll
        for (int qi = 0; qi < 2; ++qi) {
          const __half2* qh = reinterpret_cast<const __half2*>(&Qr[qi][pi]);
          acc[r][qi][0] = __hadd2(acc[r][qi][0], __habs2(__hsub2(kh[0], qh[0])));
          acc[r][qi][1] = __hadd2(acc[r][qi][1], __habs2(__hsub2(kh[1], qh[1])));
          acc[r][qi][0] = __hadd2(acc[r][qi][0], __habs2(__hsub2(kh[2], qh[2])));
          acc[r][qi][1] = __hadd2(acc[r][qi][1], __habs2(__hsub2(kh[3], qh[3])));
        }
      }
    }

    // ---- phase B: softmax for both keys (4 independent DPP/exp chains)
    __half2 wf[2][2];
#pragma unroll
    for (int r = 0; r < 2; ++r)
#pragma unroll
      for (int qi = 0; qi < 2; ++qi) {
        const __half2 s2 = __hadd2(acc[r][qi][0], acc[r][qi][1]);
        float d8p = __half2float(__low2half(s2)) + __half2float(__high2half(s2));
        const float d8 = dpp_add_f<0xB1>(d8p);          // merge half-slices (lane^1)
        const float e = __expf(-0.5f * d8 * d8);        // e <= 1
        float nrm = e;
        nrm = dpp_add_f<0x4E>(nrm);                     // lane^2
        nrm = dpp_add_f<0x141>(nrm);                    // row_half_mirror
        nrm = dpp_add_f<0x140>(nrm);                    // row_mirror
        const float w = e * __builtin_amdgcn_rcpf(nrm);
        wf[r][qi] = __float2half2_rn(w);
      }

    // ---- phase C: PV for both keys
#pragma unroll
    for (int r = 0; r < 2; ++r) {
      const u16* vrow = Vw + r * 512;
#pragma unroll
      for (int pi = 0; pi < 4; ++pi) {
        const int4 vv = *(const int4*)(vrow + grans[pi] * 8);
        const __half2* vh = reinterpret_cast<const __half2*>(&vv);
#pragma unroll
        for (int qi = 0; qi < 2; ++qi) {
          o[qi][pi][0] = __hfma2(wf[r][qi], vh[0], o[qi][pi][0]);
          o[qi][pi][1] = __hfma2(wf[r][qi], vh[1], o[qi][pi][1]);
          o[qi][pi][2] = __hfma2(wf[r][qi], vh[2], o[qi][pi][2]);
          o[qi][pi][3] = __hfma2(wf[r][qi], vh[3], o[qi][pi][3]);
        }
      }
    }
  }

  // ---- store fp16 partial (head-major layout), unrotating granules
#pragma unroll
  for (int qi = 0; qi < 2; ++qi) {
    const int j = j0 + qg + qi * 4;
    u16* dst = partial + (size_t)sp * (4096 * 512) + (size_t)(b * 1024 + j) * 512;
#pragma unroll
    for (int pi = 0; pi < 4; ++pi) {
      int4 pk; __builtin_memcpy(&pk, &o[qi][pi][0], 16);
      *(int4*)(dst + grans[pi] * 8) = pk;
    }
  }
}

// ---------------- reduce: out_pre = bf16(sum of 16 fp16 partials) ----------------
__global__ __launch_bounds__(256) void reduce_k(const u16* __restrict__ p,
                                                u16* __restrict__ out) {
  const size_t i = ((size_t)blockIdx.x * 256 + threadIdx.x) * 8;   // granule of 8 halfs
  float s[8] = {0.f, 0.f, 0.f, 0.f, 0.f, 0.f, 0.f, 0.f};
#pragma unroll
  for (int sp = 0; sp < 16; ++sp) {
    const int4 t = *(const int4*)(p + (size_t)sp * (4096 * 512) + i);
    const __half* th = reinterpret_cast<const __half*>(&t);
#pragma unroll
    for (int j = 0; j < 8; ++j) s[j] += __half2float(th[j]);
  }
  int4 pk;
  u16* pu = reinterpret_cast<u16*>(&pk);
#pragma unroll
  for (int j = 0; j < 8; ++j) pu[j] = f2bf(s[j]);
  *(int4*)(out + i) = pk;
}

// ---------------- host ----------------
extern "C" void kernel_launch(void* const* d_in, const int* in_sizes, int n_in,
                              void* d_out, int out_size, void* d_ws, size_t ws_size,
                              hipStream_t stream) {
  (void)in_sizes; (void)n_in; (void)out_size; (void)ws_size;
  char* wsp = (char*)d_ws;
  size_t off = 0;
  auto take = [&](size_t bytes) {
    void* p = (void*)(wsp + off);
    off += ((bytes + 255) & ~(size_t)255);
    return p;
  };

  static const int wR[10] = {128, 512, 512, 128, 512, 512, 128, 512, 512, 512};
  static const int wC[10] = {512, 512, 512, 512, 512, 512, 512, 512, 512, 128};
  static const int widx[10] = {3, 5, 7, 9, 11, 13, 15, 17, 19, 21};

  u16* WT[10];
  for (int i = 0; i < 10; ++i) WT[i] = (u16*)take((size_t)wR[i] * wC[i] * 2);
  u16* a0[3]; for (int i = 0; i < 3; ++i) a0[i] = (u16*)take((size_t)4096 * 128 * 2);
  u16* h1[3]; for (int i = 0; i < 3; ++i) h1[i] = (u16*)take((size_t)4096 * 512 * 2);
  u16* h2[3]; for (int i = 0; i < 3; ++i) h2[i] = (u16*)take((size_t)4096 * 512 * 2);
  u16* partial = (u16*)take((size_t)16 * 4096 * 512 * 2);   // fp16, 16 key-splits

  TransArgs ta;
  for (int i = 0; i < 10; ++i) {
    ta.src[i] = (const float*)d_in[widx[i]];
    ta.dst[i] = WT[i];
    ta.R[i] = wR[i];
    ta.C[i] = wC[i];
  }
  hipLaunchKernelGGL(transpose_k, dim3(16, 16, 10), dim3(256), 0, stream, ta);

  // convert inputs fp32 -> bf16  (0=KEY for k-MLP, 1=QUERY for q-MLP, 2=VALUE for v-MLP)
  ConvArgs ca;
  ca.src[0] = (const float*)d_in[0]; ca.src[1] = (const float*)d_in[2]; ca.src[2] = (const float*)d_in[1];
  ca.dst[0] = a0[0]; ca.dst[1] = a0[1]; ca.dst[2] = a0[2];
  hipLaunchKernelGGL(conv_k, dim3(256, 1, 3), dim3(256), 0, stream, ca);

  // layer 1: [4096x128]@[128x512]+b, relu
  GemmArgs g1 = {};
  for (int i = 0; i < 3; ++i) g1.A[i] = a0[i];
  g1.WT[0] = WT[0]; g1.WT[1] = WT[3]; g1.WT[2] = WT[6];
  g1.bias[0] = (const float*)d_in[4]; g1.bias[1] = (const float*)d_in[10]; g1.bias[2] = (const float*)d_in[16];
  g1.C[0] = h1[0]; g1.C[1] = h1[1]; g1.C[2] = h1[2];
  hipLaunchKernelGGL(gemm128, dim3(4, 32, 3), dim3(256), 0, stream, g1, 4096, 512, 128, 1, 0, 0);

  // layer 2: [4096x512]@[512x512]+b, relu
  GemmArgs g2 = {};
  for (int i = 0; i < 3; ++i) { g2.A[i] = h1[i]; g2.C[i] = h2[i]; }
  g2.WT[0] = WT[1]; g2.WT[1] = WT[4]; g2.WT[2] = WT[7];
  g2.bias[0] = (const float*)d_in[6]; g2.bias[1] = (const float*)d_in[12]; g2.bias[2] = (const float*)d_in[18];
  hipLaunchKernelGGL(gemm128, dim3(4, 32, 3), dim3(256), 0, stream, g2, 4096, 512, 512, 1, 0, 0);

  // layer 3: -> Km,Qm,Vm fp16, HEAD-MAJOR feature layout
  GemmArgs g3 = {};
  for (int i = 0; i < 3; ++i) { g3.A[i] = h2[i]; g3.C[i] = (void*)h1[i]; }
  g3.WT[0] = WT[2]; g3.WT[1] = WT[5]; g3.WT[2] = WT[8];
  g3.bias[0] = (const float*)d_in[8]; g3.bias[1] = (const float*)d_in[14]; g3.bias[2] = (const float*)d_in[20];
  hipLaunchKernelGGL(gemm128, dim3(4, 32, 3), dim3(256), 0, stream, g3, 4096, 512, 512, 0, 2, 1);

  // fused attention (16-way key split, 8 q/wave, 4 blocks/CU) -> fp16 partials
  hipLaunchKernelGGL(attn_kernel, dim3(2048), dim3(256), 0, stream, h1[0], h1[1], h1[2], partial);

  // reduce partials -> out_pre (bf16, head-major) in h2[0]
  hipLaunchKernelGGL(reduce_k, dim3(1024), dim3(256), 0, stream, partial, h2[0]);

  // final projection: [4096x512]@[512x128]+b -> d_out (fp32); WT[9] K-dim permuted to match
  GemmArgs g4 = {};
  g4.A[0] = h2[0]; g4.WT[0] = WT[9]; g4.bias[0] = (const float*)d_in[22]; g4.C[0] = d_out;
  hipLaunchKernelGGL(gemm128, dim3(1, 32, 1), dim3(256), 0, stream, g4, 4096, 128, 512, 0, 1, 0);
}

// Round 11
// 394.476 us; speedup vs baseline: 1.2206x; 1.2206x over previous
//
#include <hip/hip_runtime.h>
#include <hip/hip_bf16.h>
#include <hip/hip_fp16.h>

typedef unsigned short u16;
typedef __attribute__((ext_vector_type(8))) short short8;
typedef __attribute__((ext_vector_type(4))) float floatx4;

#define DEVI static __device__ __forceinline__

DEVI float bf2f(u16 b) { return __uint_as_float(((unsigned)b) << 16); }
DEVI u16 f2bf(float f) {
  __hip_bfloat16 h = __float2bfloat16(f);
  u16 u; __builtin_memcpy(&u, &h, 2); return u;
}
DEVI u16 f2h(float f) {
  __half h = __float2half(f);
  u16 u; __builtin_memcpy(&u, &h, 2); return u;
}

// async global->LDS, 16B per lane; LDS dest = wave-uniform base + lane*16
DEVI void async_ld16(const u16* g, u16* l) {
  __builtin_amdgcn_global_load_lds(
      (const __attribute__((address_space(1))) unsigned int*)g,
      (__attribute__((address_space(3))) unsigned int*)l, 16, 0, 0);
}

// DPP cross-lane add on float (VALU pipe)
template <int CTRL>
DEVI float dpp_add_f(float v) {
  int i; __builtin_memcpy(&i, &v, 4);
  int p = __builtin_amdgcn_update_dpp(0, i, CTRL, 0xF, 0xF, false);
  float pv; __builtin_memcpy(&pv, &p, 4);
  return v + pv;
}

// head-major permutation: feature f (= d*8+h) -> c' = h*64+d
DEVI int hperm(int f) { return ((f & 7) << 6) | (f >> 3); }

// ---------------- weight transpose + fp32->bf16: dst[C][R] = bf16(src[R][C]^T) ----------------
struct TransArgs {
  const float* src[10];
  u16* dst[10];
  int R[10];
  int C[10];
};

__global__ __launch_bounds__(256) void transpose_k(TransArgs t) {
  const int z = blockIdx.z;
  const float* __restrict__ src = t.src[z];
  u16* __restrict__ dst = t.dst[z];
  const int R = t.R[z], C = t.C[z];
  const int c0 = blockIdx.x * 32, r0 = blockIdx.y * 32;
  if (c0 >= C || r0 >= R) return;
  __shared__ float tile[32][33];
  const int tx = threadIdx.x & 31, ty = threadIdx.x >> 5;
  for (int i = ty; i < 32; i += 8)
    tile[i][tx] = src[(size_t)(r0 + i) * C + c0 + tx];
  __syncthreads();
  for (int i = ty; i < 32; i += 8) {
    const int f = r0 + tx;
    const int fi = (z == 9) ? hperm(f) : f;
    dst[(size_t)(c0 + i) * R + fi] = f2bf(tile[tx][i]);
  }
}

// ---------------- fp32 -> bf16 convert for KEY/QUERY/VALUE ----------------
struct ConvArgs {
  const float* src[3];
  u16* dst[3];
};

__global__ __launch_bounds__(256) void conv_k(ConvArgs c) {
  const int z = blockIdx.z;
  const float* __restrict__ src = c.src[z];
  u16* __restrict__ dst = c.dst[z];
  const size_t i = ((size_t)blockIdx.x * 256 + threadIdx.x) * 8;
  const float4 f0 = *(const float4*)(src + i);
  const float4 f1 = *(const float4*)(src + i + 4);
  u16 tmp[8] = {f2bf(f0.x), f2bf(f0.y), f2bf(f0.z), f2bf(f0.w),
                f2bf(f1.x), f2bf(f1.y), f2bf(f1.z), f2bf(f1.w)};
  int4 t; __builtin_memcpy(&t, tmp, 16);
  *(int4*)(dst + i) = t;
}

// ------------- GEMM 128x128 tile, async global->LDS staging (R10, measured -9.5us) -------------
struct GemmArgs {
  const u16* A[3];
  const u16* WT[3];
  const float* bias[3];
  void* C[3];
};

__global__ __launch_bounds__(256, 3) void gemm128(GemmArgs ga, int M, int N, int K,
                                                  int relu, int c_mode, int out_perm) {
  const int z = blockIdx.z;
  const u16* __restrict__ A = ga.A[z];
  const u16* __restrict__ WT = ga.WT[z];
  const float* __restrict__ bias = ga.bias[z];
  void* __restrict__ C = ga.C[z];

  __shared__ u16 As[128 * 64];
  __shared__ u16 Bs[128 * 64];

  const int tid = threadIdx.x;
  const int lane = tid & 63;
  const int wave = tid >> 6;
  const int wm = wave >> 1, wn = wave & 1;
  const int mb = blockIdx.y, nb = blockIdx.x;

  floatx4 acc[4][4];
#pragma unroll
  for (int mi = 0; mi < 4; ++mi)
#pragma unroll
    for (int ni = 0; ni < 4; ++ni) acc[mi][ni] = floatx4{0.f, 0.f, 0.f, 0.f};

  // staging: lane covers row (lane>>3) of an 8-row strip, phys granule (lane&7);
  // global column granule = phys ^ (row&7)
  const int g = (lane & 7) ^ ((lane >> 3) & 7);
  const int srow = lane >> 3;
  const size_t aRowBase = (size_t)(mb * 128 + wave * 32 + srow) * K + g * 8;
  const size_t bRowBase = (size_t)(nb * 128 + wave * 32 + srow) * K + g * 8;

  for (int k0 = 0; k0 < K; k0 += 64) {
    __syncthreads();
#pragma unroll
    for (int it = 0; it < 4; ++it) {
      async_ld16(A + aRowBase + (size_t)it * 8 * K + k0, As + (wave * 32 + it * 8) * 64);
      async_ld16(WT + bRowBase + (size_t)it * 8 * K + k0, Bs + (wave * 32 + it * 8) * 64);
    }
    __syncthreads();
#pragma unroll
    for (int ks = 0; ks < 2; ++ks) {
      const int phys = ((ks * 4 + (lane >> 4)) ^ (lane & 7)) * 8;
      short8 af[4], bf[4];
#pragma unroll
      for (int i = 0; i < 4; ++i) {
        const int m = wm * 64 + i * 16 + (lane & 15);
        const int n = wn * 64 + i * 16 + (lane & 15);
        af[i] = *(const short8*)(As + m * 64 + phys);
        bf[i] = *(const short8*)(Bs + n * 64 + phys);
      }
#pragma unroll
      for (int mi = 0; mi < 4; ++mi)
#pragma unroll
        for (int ni = 0; ni < 4; ++ni)
          acc[mi][ni] = __builtin_amdgcn_mfma_f32_16x16x32_bf16(af[mi], bf[ni], acc[mi][ni], 0, 0, 0);
    }
  }

  // C/D layout: col = lane&15, row = (lane>>4)*4 + reg
#pragma unroll
  for (int mi = 0; mi < 4; ++mi)
#pragma unroll
    for (int ni = 0; ni < 4; ++ni) {
      const int col = nb * 128 + wn * 64 + ni * 16 + (lane & 15);
      const float bv = bias[col];
      const int colw = out_perm ? hperm(col) : col;
      const floatx4 v = acc[mi][ni];
#pragma unroll
      for (int r = 0; r < 4; ++r) {
        const int row = mb * 128 + wm * 64 + mi * 16 + (lane >> 4) * 4 + r;
        float x = v[r] + bv;
        if (relu) x = fmaxf(x, 0.f);
        if (c_mode == 1)      ((float*)C)[(size_t)row * N + colw] = x;
        else if (c_mode == 2) ((u16*)C)[(size_t)row * N + colw] = f2h(x);
        else                  ((u16*)C)[(size_t)row * N + colw] = f2bf(x);
      }
    }
}

// ---------------- fused attention v5.2 (R9 verbatim: best measured, 225 us) ----------------
// 16 q/wave, 16-way key split, (256,3). Head-major features c' = h*64+d.
__global__ __launch_bounds__(256, 3) void attn_kernel(const u16* __restrict__ Km,
                                                      const u16* __restrict__ Qm,
                                                      const u16* __restrict__ Vm,
                                                      u16* __restrict__ partial) {
  __shared__ alignas(16) u16 lds[4 * 2048];   // per wave: K rows [0,1024), V rows [1024,2048) halfs

  const int tid = threadIdx.x;
  const int lane = tid & 63;
  const int wave = tid >> 6;
  const int wid = blockIdx.x * 4 + wave;      // 0..4095
  const int qt = wid & 63;
  const int sp = (wid >> 6) & 15;
  const int b = wid >> 10;
  const int j0 = qt * 16;

  const int qg = lane >> 4;
  const int h = (lane >> 1) & 7;
  const int half = lane & 1;

  int grans[4];
#pragma unroll
  for (int pi = 0; pi < 4; ++pi)
    grans[pi] = h * 8 + half * 4 + ((pi + h) & 3);

  // Q into registers: 4 queries x 4 granules (rotated order)
  int4 Qr[4][4];
#pragma unroll
  for (int qi = 0; qi < 4; ++qi) {
    const u16* qrow = Qm + (size_t)(b * 1024 + j0 + qg + qi * 4) * 512;
#pragma unroll
    for (int pi = 0; pi < 4; ++pi)
      Qr[qi][pi] = *(const int4*)(qrow + grans[pi] * 8);
  }

  __half2 o[4][4][4];   // [qi][pi][j]
#pragma unroll
  for (int qi = 0; qi < 4; ++qi)
#pragma unroll
    for (int pi = 0; pi < 4; ++pi)
#pragma unroll
      for (int j = 0; j < 4; ++j) o[qi][pi][j] = __float2half2_rn(0.f);

  u16* Kw = lds + wave * 2048;
  u16* Vw = Kw + 1024;
  const int keyBase = b * 1024 + sp * 64;

  int4 Kp[2], Vp[2];
#pragma unroll
  for (int r = 0; r < 2; ++r) {
    const size_t ga = (size_t)(keyBase + r) * 512 + lane * 8;
    Kp[r] = *(const int4*)(Km + ga);
    Vp[r] = *(const int4*)(Vm + ga);
  }

#pragma unroll 1
  for (int t = 0; t < 32; ++t) {
    // stage current 2-key chunk (linear: lane writes granule=lane; conflict-free)
#pragma unroll
    for (int r = 0; r < 2; ++r) {
      *(int4*)(Kw + r * 512 + lane * 8) = Kp[r];
      *(int4*)(Vw + r * 512 + lane * 8) = Vp[r];
    }
    // prefetch next chunk
    if (t < 31) {
#pragma unroll
      for (int r = 0; r < 2; ++r) {
        const size_t ga = (size_t)(keyBase + (t + 1) * 2 + r) * 512 + lane * 8;
        Kp[r] = *(const int4*)(Km + ga);
        Vp[r] = *(const int4*)(Vm + ga);
      }
    }

#pragma unroll
    for (int r = 0; r < 2; ++r) {
      const u16* krow = Kw + r * 512;
      // ---- cdist: packed fp16 L1 over the 32-feat slice, 4 queries
      __half2 acc[4][2];
#pragma unroll
      for (int qi = 0; qi < 4; ++qi) {
        acc[qi][0] = __float2half2_rn(0.f);
        acc[qi][1] = __float2half2_rn(0.f);
      }
#pragma unroll
      for (int pi = 0; pi < 4; ++pi) {
        const int4 kv = *(const int4*)(krow + grans[pi] * 8);
        const __half2* kh = reinterpret_cast<const __half2*>(&kv);
#pragma unroll
        for (int qi = 0; qi < 4; ++qi) {
          const __half2* qh = reinterpret_cast<const __half2*>(&Qr[qi][pi]);
          acc[qi][0] = __hadd2(acc[qi][0], __habs2(__hsub2(kh[0], qh[0])));
          acc[qi][1] = __hadd2(acc[qi][1], __habs2(__hsub2(kh[1], qh[1])));
          acc[qi][0] = __hadd2(acc[qi][0], __habs2(__hsub2(kh[2], qh[2])));
          acc[qi][1] = __hadd2(acc[qi][1], __habs2(__hsub2(kh[3], qh[3])));
        }
      }

      // ---- per-query: horizontal -> half-merge (xor1) -> softmax over heads
      __half2 wh[4];
#pragma unroll
      for (int qi = 0; qi < 4; ++qi) {
        const __half2 s2 = __hadd2(acc[qi][0], acc[qi][1]);
        float d8p = __half2float(__low2half(s2)) + __half2float(__high2half(s2));
        const float d8 = dpp_add_f<0xB1>(d8p);          // merge the two half-slices (lane^1)
        const float e = __expf(-0.5f * d8 * d8);        // e <= 1, no overflow
        float nrm = e;
        nrm = dpp_add_f<0x4E>(nrm);                     // lane^2
        nrm = dpp_add_f<0x141>(nrm);                    // row_half_mirror
        nrm = dpp_add_f<0x140>(nrm);                    // row_mirror
        const float w = e * __builtin_amdgcn_rcpf(nrm); // spans all 8 heads exactly once
        wh[qi] = __float2half2_rn(w);
      }

      // ---- PV: o += w * V over the slice
      const u16* vrow = Vw + r * 512;
#pragma unroll
      for (int pi = 0; pi < 4; ++pi) {
        const int4 vv = *(const int4*)(vrow + grans[pi] * 8);
        const __half2* vh = reinterpret_cast<const __half2*>(&vv);
#pragma unroll
        for (int qi = 0; qi < 4; ++qi) {
          o[qi][pi][0] = __hfma2(wh[qi], vh[0], o[qi][pi][0]);
          o[qi][pi][1] = __hfma2(wh[qi], vh[1], o[qi][pi][1]);
          o[qi][pi][2] = __hfma2(wh[qi], vh[2], o[qi][pi][2]);
          o[qi][pi][3] = __hfma2(wh[qi], vh[3], o[qi][pi][3]);
        }
      }
    }
  }

  // ---- store fp16 partial (head-major layout), unrotating granules
#pragma unroll
  for (int qi = 0; qi < 4; ++qi) {
    const int j = j0 + qg + qi * 4;
    u16* dst = partial + (size_t)sp * (4096 * 512) + (size_t)(b * 1024 + j) * 512;
#pragma unroll
    for (int pi = 0; pi < 4; ++pi) {
      int4 pk; __builtin_memcpy(&pk, &o[qi][pi][0], 16);
      *(int4*)(dst + grans[pi] * 8) = pk;
    }
  }
}

// ---------------- reduce: out_pre = bf16(sum of 16 fp16 partials) ----------------
__global__ __launch_bounds__(256) void reduce_k(const u16* __restrict__ p,
                                                u16* __restrict__ out) {
  const size_t i = ((size_t)blockIdx.x * 256 + threadIdx.x) * 8;   // granule of 8 halfs
  float s[8] = {0.f, 0.f, 0.f, 0.f, 0.f, 0.f, 0.f, 0.f};
#pragma unroll
  for (int sp = 0; sp < 16; ++sp) {
    const int4 t = *(const int4*)(p + (size_t)sp * (4096 * 512) + i);
    const __half* th = reinterpret_cast<const __half*>(&t);
#pragma unroll
    for (int j = 0; j < 8; ++j) s[j] += __half2float(th[j]);
  }
  int4 pk;
  u16* pu = reinterpret_cast<u16*>(&pk);
#pragma unroll
  for (int j = 0; j < 8; ++j) pu[j] = f2bf(s[j]);
  *(int4*)(out + i) = pk;
}

// ---------------- host ----------------
extern "C" void kernel_launch(void* const* d_in, const int* in_sizes, int n_in,
                              void* d_out, int out_size, void* d_ws, size_t ws_size,
                              hipStream_t stream) {
  (void)in_sizes; (void)n_in; (void)out_size; (void)ws_size;
  char* wsp = (char*)d_ws;
  size_t off = 0;
  auto take = [&](size_t bytes) {
    void* p = (void*)(wsp + off);
    off += ((bytes + 255) & ~(size_t)255);
    return p;
  };

  static const int wR[10] = {128, 512, 512, 128, 512, 512, 128, 512, 512, 512};
  static const int wC[10] = {512, 512, 512, 512, 512, 512, 512, 512, 512, 128};
  static const int widx[10] = {3, 5, 7, 9, 11, 13, 15, 17, 19, 21};

  u16* WT[10];
  for (int i = 0; i < 10; ++i) WT[i] = (u16*)take((size_t)wR[i] * wC[i] * 2);
  u16* a0[3]; for (int i = 0; i < 3; ++i) a0[i] = (u16*)take((size_t)4096 * 128 * 2);
  u16* h1[3]; for (int i = 0; i < 3; ++i) h1[i] = (u16*)take((size_t)4096 * 512 * 2);
  u16* h2[3]; for (int i = 0; i < 3; ++i) h2[i] = (u16*)take((size_t)4096 * 512 * 2);
  u16* partial = (u16*)take((size_t)16 * 4096 * 512 * 2);   // fp16, 16 key-splits

  TransArgs ta;
  for (int i = 0; i < 10; ++i) {
    ta.src[i] = (const float*)d_in[widx[i]];
    ta.dst[i] = WT[i];
    ta.R[i] = wR[i];
    ta.C[i] = wC[i];
  }
  hipLaunchKernelGGL(transpose_k, dim3(16, 16, 10), dim3(256), 0, stream, ta);

  // convert inputs fp32 -> bf16  (0=KEY for k-MLP, 1=QUERY for q-MLP, 2=VALUE for v-MLP)
  ConvArgs ca;
  ca.src[0] = (const float*)d_in[0]; ca.src[1] = (const float*)d_in[2]; ca.src[2] = (const float*)d_in[1];
  ca.dst[0] = a0[0]; ca.dst[1] = a0[1]; ca.dst[2] = a0[2];
  hipLaunchKernelGGL(conv_k, dim3(256, 1, 3), dim3(256), 0, stream, ca);

  // layer 1: [4096x128]@[128x512]+b, relu
  GemmArgs g1 = {};
  for (int i = 0; i < 3; ++i) g1.A[i] = a0[i];
  g1.WT[0] = WT[0]; g1.WT[1] = WT[3]; g1.WT[2] = WT[6];
  g1.bias[0] = (const float*)d_in[4]; g1.bias[1] = (const float*)d_in[10]; g1.bias[2] = (const float*)d_in[16];
  g1.C[0] = h1[0]; g1.C[1] = h1[1]; g1.C[2] = h1[2];
  hipLaunchKernelGGL(gemm128, dim3(4, 32, 3), dim3(256), 0, stream, g1, 4096, 512, 128, 1, 0, 0);

  // layer 2: [4096x512]@[512x512]+b, relu
  GemmArgs g2 = {};
  for (int i = 0; i < 3; ++i) { g2.A[i] = h1[i]; g2.C[i] = h2[i]; }
  g2.WT[0] = WT[1]; g2.WT[1] = WT[4]; g2.WT[2] = WT[7];
  g2.bias[0] = (const float*)d_in[6]; g2.bias[1] = (const float*)d_in[12]; g2.bias[2] = (const float*)d_in[18];
  hipLaunchKernelGGL(gemm128, dim3(4, 32, 3), dim3(256), 0, stream, g2, 4096, 512, 512, 1, 0, 0);

  // layer 3: -> Km,Qm,Vm fp16, HEAD-MAJOR feature layout
  GemmArgs g3 = {};
  for (int i = 0; i < 3; ++i) { g3.A[i] = h2[i]; g3.C[i] = (void*)h1[i]; }
  g3.WT[0] = WT[2]; g3.WT[1] = WT[5]; g3.WT[2] = WT[8];
  g3.bias[0] = (const float*)d_in[8]; g3.bias[1] = (const float*)d_in[14]; g3.bias[2] = (const float*)d_in[20];
  hipLaunchKernelGGL(gemm128, dim3(4, 32, 3), dim3(256), 0, stream, g3, 4096, 512, 512, 0, 2, 1);

  // fused attention (16-way key split, 16 q/wave, (256,3)) -> fp16 partials
  hipLaunchKernelGGL(attn_kernel, dim3(1024), dim3(256), 0, stream, h1[0], h1[1], h1[2], partial);

  // reduce partials -> out_pre (bf16, head-major) in h2[0]
  hipLaunchKernelGGL(reduce_k, dim3(1024), dim3(256), 0, stream, partial, h2[0]);

  // final projection: [4096x512]@[512x128]+b -> d_out (fp32); WT[9] K-dim permuted to match
  GemmArgs g4 = {};
  g4.A[0] = h2[0]; g4.WT[0] = WT[9]; g4.bias[0] = (const float*)d_in[22]; g4.C[0] = d_out;
  hipLaunchKernelGGL(gemm128, dim3(1, 32, 1), dim3(256), 0, stream, g4, 4096, 128, 512, 0, 1, 0);
}